// Round 5
// baseline (516.830 us; speedup 1.0000x reference)
//
#include <hip/hip_runtime.h>
#include <math.h>

// Shape: B=16, C=256, H=W=128, HW=16384. x = 256 MiB fp32 (== L3 size; no reuse
// across passes — measured: reversal/boustrophedon gave 0; treat as pure HBM).
// K1 stats+median: per (b,c) block -> mean,max,std(ddof=1) -> u[B][C][3];
//     LAST block of each batch (device-scope acq_rel counter) computes the
//     median of the 768 stats + cubed dev + dw-conv1d(3) + BN + sigmoid -> g.
// K2 scale: per (b,c) block, out = x * g[bc]; nt load + nt store, 8-deep MLP.

typedef float fvec4 __attribute__((ext_vector_type(4)));

__global__ void stats_median_kernel(const float* __restrict__ x,
                                    const float* __restrict__ w,
                                    const float* __restrict__ gamma,
                                    const float* __restrict__ beta,
                                    const float* __restrict__ rmean,
                                    const float* __restrict__ rvar,
                                    float* __restrict__ u,
                                    float* __restrict__ g,
                                    int* __restrict__ ctr,
                                    int HW, int C) {
    const int bc  = blockIdx.x;
    const int b   = bc / C;
    const int tid = threadIdx.x;
    const float4* __restrict__ x4 =
        (const float4*)(x + (size_t)bc * (size_t)HW);
    const int n4 = HW >> 2;

    float s0 = 0.f, q0 = 0.f, m0 = -INFINITY;
    float s1 = 0.f, q1 = 0.f, m1 = -INFINITY;
    float s2 = 0.f, q2 = 0.f, m2 = -INFINITY;
    float s3 = 0.f, q3 = 0.f, m3 = -INFINITY;

    if (n4 == 4096) {
        #pragma unroll
        for (int k = 0; k < 4; ++k) {
            float4 a = x4[tid + (k * 4 + 0) * 256];
            float4 bb = x4[tid + (k * 4 + 1) * 256];
            float4 c = x4[tid + (k * 4 + 2) * 256];
            float4 d = x4[tid + (k * 4 + 3) * 256];
            s0 += (a.x + a.y) + (a.z + a.w);
            q0 += (a.x * a.x + a.y * a.y) + (a.z * a.z + a.w * a.w);
            m0 = fmaxf(m0, fmaxf(fmaxf(a.x, a.y), fmaxf(a.z, a.w)));
            s1 += (bb.x + bb.y) + (bb.z + bb.w);
            q1 += (bb.x * bb.x + bb.y * bb.y) + (bb.z * bb.z + bb.w * bb.w);
            m1 = fmaxf(m1, fmaxf(fmaxf(bb.x, bb.y), fmaxf(bb.z, bb.w)));
            s2 += (c.x + c.y) + (c.z + c.w);
            q2 += (c.x * c.x + c.y * c.y) + (c.z * c.z + c.w * c.w);
            m2 = fmaxf(m2, fmaxf(fmaxf(c.x, c.y), fmaxf(c.z, c.w)));
            s3 += (d.x + d.y) + (d.z + d.w);
            q3 += (d.x * d.x + d.y * d.y) + (d.z * d.z + d.w * d.w);
            m3 = fmaxf(m3, fmaxf(fmaxf(d.x, d.y), fmaxf(d.z, d.w)));
        }
    } else {
        for (int i = tid; i < n4; i += 256) {
            float4 a = x4[i];
            s0 += (a.x + a.y) + (a.z + a.w);
            q0 += (a.x * a.x + a.y * a.y) + (a.z * a.z + a.w * a.w);
            m0 = fmaxf(m0, fmaxf(fmaxf(a.x, a.y), fmaxf(a.z, a.w)));
        }
    }
    float s = (s0 + s1) + (s2 + s3);
    float q = (q0 + q1) + (q2 + q3);
    float mx = fmaxf(fmaxf(m0, m1), fmaxf(m2, m3));

    for (int off = 32; off > 0; off >>= 1) {
        s  += __shfl_down(s, off);
        q  += __shfl_down(q, off);
        mx  = fmaxf(mx, __shfl_down(mx, off));
    }
    __shared__ float ss[4], sq[4], sm[4];
    const int wid = tid >> 6, lane = tid & 63;
    if (lane == 0) { ss[wid] = s; sq[wid] = q; sm[wid] = mx; }
    __syncthreads();

    __shared__ int is_last;
    if (tid == 0) {
        float S = ss[0] + ss[1] + ss[2] + ss[3];
        float Q = sq[0] + sq[1] + sq[2] + sq[3];
        float M = fmaxf(fmaxf(sm[0], sm[1]), fmaxf(sm[2], sm[3]));
        float mean = S / (float)HW;
        float var  = (Q - S * mean) / (float)(HW - 1);  // unbiased (ddof=1)
        var = fmaxf(var, 0.f);
        float* up = u + (size_t)bc * 3;
        up[0] = mean;
        up[1] = M;
        up[2] = sqrtf(var);
        __threadfence();  // make up[] visible device-wide before the ticket
        int old = __hip_atomic_fetch_add(&ctr[b], 1, __ATOMIC_ACQ_REL,
                                         __HIP_MEMORY_SCOPE_AGENT);
        is_last = (old == C - 1);
    }
    __syncthreads();
    if (!is_last) return;

    // ---- last block of batch b: median + gate for all C channels ----
    const int NV = C * 3;  // 768
    __shared__ float sv[768];
    __shared__ float ma, mb;
    const float* ub = u + (size_t)b * NV;
    for (int i = tid; i < NV; i += 256) sv[i] = ub[i];
    __syncthreads();

    float v0 = sv[tid], v1 = sv[tid + 256], v2 = sv[tid + 512];
    int lt0 = 0, eq0 = 0, lt1 = 0, eq1 = 0, lt2 = 0, eq2 = 0;
    for (int i = 0; i < NV; ++i) {
        float o = sv[i];
        lt0 += (o < v0); eq0 += (o == v0);
        lt1 += (o < v1); eq1 += (o == v1);
        lt2 += (o < v2); eq2 += (o == v2);
    }
    const int r0 = (NV - 1) / 2;  // 383
    const int r1 = NV / 2;        // 384
    if (lt0 <= r0 && r0 < lt0 + eq0) ma = v0;
    if (lt1 <= r0 && r0 < lt1 + eq1) ma = v1;
    if (lt2 <= r0 && r0 < lt2 + eq2) ma = v2;
    if (lt0 <= r1 && r1 < lt0 + eq0) mb = v0;
    if (lt1 <= r1 && r1 < lt1 + eq1) mb = v1;
    if (lt2 <= r1 && r1 < lt2 + eq2) mb = v2;
    __syncthreads();

    const float med = 0.5f * (ma + mb);
    if (tid < C) {
        const int c = tid;
        float z = 0.f;
        #pragma unroll
        for (int k = 0; k < 3; ++k) {
            float d = sv[c * 3 + k] - med;
            z += (d * d * d) * w[c * 3 + k];
        }
        z = (z - rmean[c]) * rsqrtf(rvar[c] + 1e-5f) * gamma[c] + beta[c];
        g[(size_t)b * C + c] = 1.f / (1.f + expf(-z));
    }
}

// One block per (b,c), forward order; g wave-uniform; nt load + nt store,
// 8 loads in flight before the stores (deep MLP for the mixed stream).
__global__ void scale_kernel(const float* __restrict__ x,
                             const float* __restrict__ g,
                             float* __restrict__ out, int HW) {
    const int bc = blockIdx.x;
    const float gv = g[bc];
    const size_t base = (size_t)bc * (size_t)HW;
    const fvec4* __restrict__ x4 = (const fvec4*)(x + base);
    fvec4* __restrict__ o4 = (fvec4*)(out + base);
    const int n4 = HW >> 2;
    if (n4 == 4096) {
        #pragma unroll
        for (int half = 0; half < 2; ++half) {
            const int bi = (int)threadIdx.x + half * 2048;
            fvec4 r[8];
            #pragma unroll
            for (int k = 0; k < 8; ++k)
                r[k] = __builtin_nontemporal_load(&x4[bi + k * 256]);
            #pragma unroll
            for (int k = 0; k < 8; ++k)
                __builtin_nontemporal_store(r[k] * gv, &o4[bi + k * 256]);
        }
    } else {
        for (int i = threadIdx.x; i < n4; i += 256) {
            fvec4 v = __builtin_nontemporal_load(&x4[i]);
            __builtin_nontemporal_store(v * gv, &o4[i]);
        }
    }
}

extern "C" void kernel_launch(void* const* d_in, const int* in_sizes, int n_in,
                              void* d_out, int out_size, void* d_ws, size_t ws_size,
                              hipStream_t stream) {
    const float* x     = (const float*)d_in[0];
    const float* w     = (const float*)d_in[1];
    const float* gamma = (const float*)d_in[2];
    const float* beta  = (const float*)d_in[3];
    const float* rmean = (const float*)d_in[4];
    const float* rvar  = (const float*)d_in[5];
    float* out = (float*)d_out;

    const int C  = in_sizes[2];              // 256 (gamma)
    const int B  = 16;
    const int HW = in_sizes[0] / (B * C);    // 16384

    float* u   = (float*)d_ws;               // [B][C][3]
    float* g   = u + (size_t)B * C * 3;      // [B][C]
    int*   ctr = (int*)(g + (size_t)B * C);  // [B]

    // zero the per-batch tickets every launch (graph-capture-safe, makes
    // the launch deterministic across replays despite stale ws contents)
    hipMemsetAsync(ctr, 0, B * sizeof(int), stream);

    stats_median_kernel<<<B * C, 256, 0, stream>>>(x, w, gamma, beta, rmean,
                                                   rvar, u, g, ctr, HW, C);
    scale_kernel<<<B * C, 256, 0, stream>>>(x, g, out, HW);
}

// Round 6
// 161.684 us; speedup vs baseline: 3.1966x; 3.1966x over previous
//
#include <hip/hip_runtime.h>
#include <math.h>

// Shape: B=16, C=256, H=W=128, HW=16384. x = 256 MiB fp32.
// Measured facts so far:
//  - L3 reuse across passes: none (boustrophedon neutral). Treat as pure HBM.
//  - Device-scope atomic/fence fusion: catastrophic (-360 µs). Reverted.
// Structure: 3 kernels, forward order.
//  K1 stats:  per (b,c) block -> mean, max, std(ddof=1) -> u[B][C][3]
//  K2 median+gate: per batch -> median of 768 stats (register rank-select),
//     cubed dev, dw-conv1d(3), BN eval, sigmoid -> g[B][C]
//  K3 scale:  per (b,c) block -> out = x * g[bc]; nt load + nt store, 8-deep.

typedef float fvec4 __attribute__((ext_vector_type(4)));

__global__ void stats_kernel(const float* __restrict__ x,
                             float* __restrict__ u, int HW) {
    const int bc  = blockIdx.x;
    const int tid = threadIdx.x;
    const float4* __restrict__ x4 =
        (const float4*)(x + (size_t)bc * (size_t)HW);
    const int n4 = HW >> 2;

    float s0 = 0.f, q0 = 0.f, m0 = -INFINITY;
    float s1 = 0.f, q1 = 0.f, m1 = -INFINITY;
    float s2 = 0.f, q2 = 0.f, m2 = -INFINITY;
    float s3 = 0.f, q3 = 0.f, m3 = -INFINITY;

    if (n4 == 4096) {
        // static fast path: 16 float4 per thread, 4 independent chains
        #pragma unroll
        for (int k = 0; k < 4; ++k) {
            float4 a = x4[tid + (k * 4 + 0) * 256];
            float4 b = x4[tid + (k * 4 + 1) * 256];
            float4 c = x4[tid + (k * 4 + 2) * 256];
            float4 d = x4[tid + (k * 4 + 3) * 256];
            s0 += (a.x + a.y) + (a.z + a.w);
            q0 += (a.x * a.x + a.y * a.y) + (a.z * a.z + a.w * a.w);
            m0 = fmaxf(m0, fmaxf(fmaxf(a.x, a.y), fmaxf(a.z, a.w)));
            s1 += (b.x + b.y) + (b.z + b.w);
            q1 += (b.x * b.x + b.y * b.y) + (b.z * b.z + b.w * b.w);
            m1 = fmaxf(m1, fmaxf(fmaxf(b.x, b.y), fmaxf(b.z, b.w)));
            s2 += (c.x + c.y) + (c.z + c.w);
            q2 += (c.x * c.x + c.y * c.y) + (c.z * c.z + c.w * c.w);
            m2 = fmaxf(m2, fmaxf(fmaxf(c.x, c.y), fmaxf(c.z, c.w)));
            s3 += (d.x + d.y) + (d.z + d.w);
            q3 += (d.x * d.x + d.y * d.y) + (d.z * d.z + d.w * d.w);
            m3 = fmaxf(m3, fmaxf(fmaxf(d.x, d.y), fmaxf(d.z, d.w)));
        }
    } else {
        for (int i = tid; i < n4; i += 256) {
            float4 a = x4[i];
            s0 += (a.x + a.y) + (a.z + a.w);
            q0 += (a.x * a.x + a.y * a.y) + (a.z * a.z + a.w * a.w);
            m0 = fmaxf(m0, fmaxf(fmaxf(a.x, a.y), fmaxf(a.z, a.w)));
        }
    }
    float s = (s0 + s1) + (s2 + s3);
    float q = (q0 + q1) + (q2 + q3);
    float mx = fmaxf(fmaxf(m0, m1), fmaxf(m2, m3));

    for (int off = 32; off > 0; off >>= 1) {
        s  += __shfl_down(s, off);
        q  += __shfl_down(q, off);
        mx  = fmaxf(mx, __shfl_down(mx, off));
    }
    __shared__ float ss[4], sq[4], sm[4];
    const int wid = tid >> 6, lane = tid & 63;
    if (lane == 0) { ss[wid] = s; sq[wid] = q; sm[wid] = mx; }
    __syncthreads();
    if (tid == 0) {
        float S = ss[0] + ss[1] + ss[2] + ss[3];
        float Q = sq[0] + sq[1] + sq[2] + sq[3];
        float M = fmaxf(fmaxf(sm[0], sm[1]), fmaxf(sm[2], sm[3]));
        float mean = S / (float)HW;
        float var  = (Q - S * mean) / (float)(HW - 1);  // unbiased (ddof=1)
        var = fmaxf(var, 0.f);
        float* up = u + (size_t)bc * 3;
        up[0] = mean;
        up[1] = M;
        up[2] = sqrtf(var);
    }
}

// One block per batch. NV = C*3 = 768; median = mean of ranks 383,384.
// Each thread owns 3 candidates in registers; one LDS sweep counts ranks.
__global__ void median_gate_kernel(const float* __restrict__ u,
                                   const float* __restrict__ w,
                                   const float* __restrict__ gamma,
                                   const float* __restrict__ beta,
                                   const float* __restrict__ rmean,
                                   const float* __restrict__ rvar,
                                   float* __restrict__ g, int C) {
    const int b   = blockIdx.x;
    const int tid = threadIdx.x;
    const int NV  = C * 3;  // 768
    __shared__ float sv[768];
    __shared__ float ma, mb;

    const float* ub = u + (size_t)b * NV;
    for (int i = tid; i < NV; i += 256) sv[i] = ub[i];
    __syncthreads();

    float v0 = sv[tid], v1 = sv[tid + 256], v2 = sv[tid + 512];
    int lt0 = 0, eq0 = 0, lt1 = 0, eq1 = 0, lt2 = 0, eq2 = 0;
    for (int i = 0; i < NV; ++i) {
        float o = sv[i];
        lt0 += (o < v0); eq0 += (o == v0);
        lt1 += (o < v1); eq1 += (o == v1);
        lt2 += (o < v2); eq2 += (o == v2);
    }
    const int r0 = (NV - 1) / 2;  // 383
    const int r1 = NV / 2;        // 384
    if (lt0 <= r0 && r0 < lt0 + eq0) ma = v0;
    if (lt1 <= r0 && r0 < lt1 + eq1) ma = v1;
    if (lt2 <= r0 && r0 < lt2 + eq2) ma = v2;
    if (lt0 <= r1 && r1 < lt0 + eq0) mb = v0;
    if (lt1 <= r1 && r1 < lt1 + eq1) mb = v1;
    if (lt2 <= r1 && r1 < lt2 + eq2) mb = v2;
    __syncthreads();

    const float med = 0.5f * (ma + mb);
    if (tid < C) {
        const int c = tid;
        float z = 0.f;
        #pragma unroll
        for (int k = 0; k < 3; ++k) {
            float d = sv[c * 3 + k] - med;
            z += (d * d * d) * w[c * 3 + k];
        }
        z = (z - rmean[c]) * rsqrtf(rvar[c] + 1e-5f) * gamma[c] + beta[c];
        g[(size_t)b * C + c] = 1.f / (1.f + expf(-z));
    }
}

// One block per (b,c); g wave-uniform; nt load + nt store, 8 loads in
// flight before the stores (deep MLP on the mixed stream).
__global__ void scale_kernel(const float* __restrict__ x,
                             const float* __restrict__ g,
                             float* __restrict__ out, int HW) {
    const int bc = blockIdx.x;
    const float gv = g[bc];
    const size_t base = (size_t)bc * (size_t)HW;
    const fvec4* __restrict__ x4 = (const fvec4*)(x + base);
    fvec4* __restrict__ o4 = (fvec4*)(out + base);
    const int n4 = HW >> 2;
    if (n4 == 4096) {
        #pragma unroll
        for (int half = 0; half < 2; ++half) {
            const int bi = (int)threadIdx.x + half * 2048;
            fvec4 r[8];
            #pragma unroll
            for (int k = 0; k < 8; ++k)
                r[k] = __builtin_nontemporal_load(&x4[bi + k * 256]);
            #pragma unroll
            for (int k = 0; k < 8; ++k)
                __builtin_nontemporal_store(r[k] * gv, &o4[bi + k * 256]);
        }
    } else {
        for (int i = threadIdx.x; i < n4; i += 256) {
            fvec4 v = __builtin_nontemporal_load(&x4[i]);
            __builtin_nontemporal_store(v * gv, &o4[i]);
        }
    }
}

extern "C" void kernel_launch(void* const* d_in, const int* in_sizes, int n_in,
                              void* d_out, int out_size, void* d_ws, size_t ws_size,
                              hipStream_t stream) {
    const float* x     = (const float*)d_in[0];
    const float* w     = (const float*)d_in[1];
    const float* gamma = (const float*)d_in[2];
    const float* beta  = (const float*)d_in[3];
    const float* rmean = (const float*)d_in[4];
    const float* rvar  = (const float*)d_in[5];
    float* out = (float*)d_out;

    const int C  = in_sizes[2];              // 256 (gamma)
    const int B  = 16;
    const int HW = in_sizes[0] / (B * C);    // 16384

    float* u = (float*)d_ws;                 // [B][C][3]
    float* g = u + (size_t)B * C * 3;        // [B][C]

    stats_kernel<<<B * C, 256, 0, stream>>>(x, u, HW);
    median_gate_kernel<<<B, 256, 0, stream>>>(u, w, gamma, beta, rmean, rvar, g, C);
    scale_kernel<<<B * C, 256, 0, stream>>>(x, g, out, HW);
}

// Round 7
// 159.776 us; speedup vs baseline: 3.2347x; 1.0119x over previous
//
#include <hip/hip_runtime.h>
#include <math.h>

// Shape: B=16, C=256, H=W=128, HW=16384. x = 256 MiB fp32.
// Measured facts:
//  - L3 reuse across passes: none (boustrophedon neutral). Pure HBM op.
//  - Device-scope atomic/fence fusion: catastrophic (+355 µs). Never again.
//  - nt-load: neutral-to-slightly-negative. nt-store: keep (write stream).
// Structure: 3 kernels, forward order.
//  K1 stats:  per (b,c) block -> mean, max, std(ddof=1) -> u[B][C][3]
//             batch-8 register loads then reduce (8 loads in flight/thread)
//  K2 median+gate: per batch -> median of 768 stats (register rank-select),
//     cubed dev, dw-conv1d(3), BN eval, sigmoid -> g[B][C]
//  K3 scale:  per (b,c) block -> out = x * g[bc]; batch-8 loads + nt stores.

typedef float fvec4 __attribute__((ext_vector_type(4)));

__global__ __launch_bounds__(256) void stats_kernel(
        const float* __restrict__ x, float* __restrict__ u, int HW) {
    const int bc  = blockIdx.x;
    const int tid = threadIdx.x;
    const float4* __restrict__ x4 =
        (const float4*)(x + (size_t)bc * (size_t)HW);
    const int n4 = HW >> 2;

    float s0 = 0.f, q0 = 0.f, m0 = -INFINITY;
    float s1 = 0.f, q1 = 0.f, m1 = -INFINITY;
    float s2 = 0.f, q2 = 0.f, m2 = -INFINITY;
    float s3 = 0.f, q3 = 0.f, m3 = -INFINITY;

    if (n4 == 4096) {
        // 16 float4/thread in 2 batches of 8: load-all, then reduce.
        #pragma unroll
        for (int half = 0; half < 2; ++half) {
            float4 r[8];
            const int bi = tid + half * 2048;
            #pragma unroll
            for (int k = 0; k < 8; ++k) r[k] = x4[bi + k * 256];
            #pragma unroll
            for (int k = 0; k < 8; k += 4) {
                float4 a = r[k], b = r[k + 1], c = r[k + 2], d = r[k + 3];
                s0 += (a.x + a.y) + (a.z + a.w);
                q0 += (a.x * a.x + a.y * a.y) + (a.z * a.z + a.w * a.w);
                m0 = fmaxf(m0, fmaxf(fmaxf(a.x, a.y), fmaxf(a.z, a.w)));
                s1 += (b.x + b.y) + (b.z + b.w);
                q1 += (b.x * b.x + b.y * b.y) + (b.z * b.z + b.w * b.w);
                m1 = fmaxf(m1, fmaxf(fmaxf(b.x, b.y), fmaxf(b.z, b.w)));
                s2 += (c.x + c.y) + (c.z + c.w);
                q2 += (c.x * c.x + c.y * c.y) + (c.z * c.z + c.w * c.w);
                m2 = fmaxf(m2, fmaxf(fmaxf(c.x, c.y), fmaxf(c.z, c.w)));
                s3 += (d.x + d.y) + (d.z + d.w);
                q3 += (d.x * d.x + d.y * d.y) + (d.z * d.z + d.w * d.w);
                m3 = fmaxf(m3, fmaxf(fmaxf(d.x, d.y), fmaxf(d.z, d.w)));
            }
        }
    } else {
        for (int i = tid; i < n4; i += 256) {
            float4 a = x4[i];
            s0 += (a.x + a.y) + (a.z + a.w);
            q0 += (a.x * a.x + a.y * a.y) + (a.z * a.z + a.w * a.w);
            m0 = fmaxf(m0, fmaxf(fmaxf(a.x, a.y), fmaxf(a.z, a.w)));
        }
    }
    float s = (s0 + s1) + (s2 + s3);
    float q = (q0 + q1) + (q2 + q3);
    float mx = fmaxf(fmaxf(m0, m1), fmaxf(m2, m3));

    for (int off = 32; off > 0; off >>= 1) {
        s  += __shfl_down(s, off);
        q  += __shfl_down(q, off);
        mx  = fmaxf(mx, __shfl_down(mx, off));
    }
    __shared__ float ss[4], sq[4], sm[4];
    const int wid = tid >> 6, lane = tid & 63;
    if (lane == 0) { ss[wid] = s; sq[wid] = q; sm[wid] = mx; }
    __syncthreads();
    if (tid == 0) {
        float S = ss[0] + ss[1] + ss[2] + ss[3];
        float Q = sq[0] + sq[1] + sq[2] + sq[3];
        float M = fmaxf(fmaxf(sm[0], sm[1]), fmaxf(sm[2], sm[3]));
        float mean = S / (float)HW;
        float var  = (Q - S * mean) / (float)(HW - 1);  // unbiased (ddof=1)
        var = fmaxf(var, 0.f);
        float* up = u + (size_t)bc * 3;
        up[0] = mean;
        up[1] = M;
        up[2] = sqrtf(var);
    }
}

// One block per batch. NV = C*3 = 768; median = mean of ranks 383,384.
__global__ void median_gate_kernel(const float* __restrict__ u,
                                   const float* __restrict__ w,
                                   const float* __restrict__ gamma,
                                   const float* __restrict__ beta,
                                   const float* __restrict__ rmean,
                                   const float* __restrict__ rvar,
                                   float* __restrict__ g, int C) {
    const int b   = blockIdx.x;
    const int tid = threadIdx.x;
    const int NV  = C * 3;  // 768
    __shared__ float sv[768];
    __shared__ float ma, mb;

    const float* ub = u + (size_t)b * NV;
    for (int i = tid; i < NV; i += 256) sv[i] = ub[i];
    __syncthreads();

    float v0 = sv[tid], v1 = sv[tid + 256], v2 = sv[tid + 512];
    int lt0 = 0, eq0 = 0, lt1 = 0, eq1 = 0, lt2 = 0, eq2 = 0;
    for (int i = 0; i < NV; ++i) {
        float o = sv[i];
        lt0 += (o < v0); eq0 += (o == v0);
        lt1 += (o < v1); eq1 += (o == v1);
        lt2 += (o < v2); eq2 += (o == v2);
    }
    const int r0 = (NV - 1) / 2;  // 383
    const int r1 = NV / 2;        // 384
    if (lt0 <= r0 && r0 < lt0 + eq0) ma = v0;
    if (lt1 <= r0 && r0 < lt1 + eq1) ma = v1;
    if (lt2 <= r0 && r0 < lt2 + eq2) ma = v2;
    if (lt0 <= r1 && r1 < lt0 + eq0) mb = v0;
    if (lt1 <= r1 && r1 < lt1 + eq1) mb = v1;
    if (lt2 <= r1 && r1 < lt2 + eq2) mb = v2;
    __syncthreads();

    const float med = 0.5f * (ma + mb);
    if (tid < C) {
        const int c = tid;
        float z = 0.f;
        #pragma unroll
        for (int k = 0; k < 3; ++k) {
            float d = sv[c * 3 + k] - med;
            z += (d * d * d) * w[c * 3 + k];
        }
        z = (z - rmean[c]) * rsqrtf(rvar[c] + 1e-5f) * gamma[c] + beta[c];
        g[(size_t)b * C + c] = 1.f / (1.f + expf(-z));
    }
}

// One block per (b,c); g wave-uniform; batch-8 regular loads + nt stores.
__global__ __launch_bounds__(256) void scale_kernel(
        const float* __restrict__ x, const float* __restrict__ g,
        float* __restrict__ out, int HW) {
    const int bc = blockIdx.x;
    const float gv = g[bc];
    const size_t base = (size_t)bc * (size_t)HW;
    const fvec4* __restrict__ x4 = (const fvec4*)(x + base);
    fvec4* __restrict__ o4 = (fvec4*)(out + base);
    const int n4 = HW >> 2;
    if (n4 == 4096) {
        #pragma unroll
        for (int half = 0; half < 2; ++half) {
            const int bi = (int)threadIdx.x + half * 2048;
            fvec4 r[8];
            #pragma unroll
            for (int k = 0; k < 8; ++k)
                r[k] = x4[bi + k * 256];
            #pragma unroll
            for (int k = 0; k < 8; ++k)
                __builtin_nontemporal_store(r[k] * gv, &o4[bi + k * 256]);
        }
    } else {
        for (int i = threadIdx.x; i < n4; i += 256) {
            fvec4 v = x4[i];
            __builtin_nontemporal_store(v * gv, &o4[i]);
        }
    }
}

extern "C" void kernel_launch(void* const* d_in, const int* in_sizes, int n_in,
                              void* d_out, int out_size, void* d_ws, size_t ws_size,
                              hipStream_t stream) {
    const float* x     = (const float*)d_in[0];
    const float* w     = (const float*)d_in[1];
    const float* gamma = (const float*)d_in[2];
    const float* beta  = (const float*)d_in[3];
    const float* rmean = (const float*)d_in[4];
    const float* rvar  = (const float*)d_in[5];
    float* out = (float*)d_out;

    const int C  = in_sizes[2];              // 256 (gamma)
    const int B  = 16;
    const int HW = in_sizes[0] / (B * C);    // 16384

    float* u = (float*)d_ws;                 // [B][C][3]
    float* g = u + (size_t)B * C * 3;        // [B][C]

    stats_kernel<<<B * C, 256, 0, stream>>>(x, u, HW);
    median_gate_kernel<<<B, 256, 0, stream>>>(u, w, gamma, beta, rmean, rvar, g, C);
    scale_kernel<<<B * C, 256, 0, stream>>>(x, g, out, HW);
}